// Round 4
// baseline (55.261 us; speedup 1.0000x reference)
//
#include <hip/hip_runtime.h>
#include <hip/hip_bf16.h>

// Lovasz-Softmax loss, B=8, N=262144 (2^18), C=21, ignore_index=0.
// R4: per-block LDS histograms flushed via skip-if-zero global u32 atomics
// directly into the final 320KB histogram (no 21MB partials roundtrip).
// H=256 buckets; closed-form per-bucket Lovasz gradient in K2.

#define B_DIM 8
#define N_DIM 262144          // 2^18
#define NCLS 20               // classes 1..20
#define HB 256                // buckets
#define PX_PER_BLK 2048       // K1: 512 threads x 4 pixels
#define BLKS_PER_B 128        // 262144 / 2048
#define NBLK1 (B_DIM * BLKS_PER_B)   // 1024
#define HSLOT (NCLS * HB)     // 5120 u32 per histogram (one batch)

// ---------------------------------------------------------------------------
// Kernel 1: softmax + error bucketing -> LDS histogram (2 replicas split by
// half-wave, +1-u32 skew) -> skip-if-zero global atomic flush into
// gh0/gh1[b][c-1][h] (bg / fg counts, u32).
// ---------------------------------------------------------------------------
__global__ __launch_bounds__(512) void lovasz_hist1_kernel(
    const float* __restrict__ logits, const int* __restrict__ labels,
    unsigned* __restrict__ gh0, unsigned* __restrict__ gh1) {
  __shared__ unsigned hist[2 * HSLOT + 1];
  const int tid = threadIdx.x;

  for (int i = tid; i < 2 * HSLOT + 1; i += 512) hist[i] = 0;
  __syncthreads();

  unsigned* myh = hist + ((tid >> 5) & 1) * (HSLOT + 1);
  const size_t base = (size_t)blockIdx.x * PX_PER_BLK;

  #pragma unroll
  for (int j = 0; j < 4; ++j) {
    const size_t p = base + tid + j * 512;
    const int lab = labels[p];
    const float* lp = logits + p * 21;
    float ex[21];
    float denom = 0.f;
    #pragma unroll
    for (int c = 0; c < 21; ++c) {
      ex[c] = __expf(lp[c]);
      denom += ex[c];
    }
    const float inv = 1.0f / denom;
    if (lab != 0) {
      #pragma unroll
      for (int c = 1; c <= NCLS; ++c) {
        const float pc = ex[c] * inv;
        const bool fg = (lab == c);
        const float e = fg ? (1.0f - pc) : pc;     // in (0,1)
        int h = (int)(e * (float)HB);
        h = h < (HB - 1) ? h : (HB - 1);
        atomicAdd(&myh[(c - 1) * HB + h], fg ? 0x10000u : 1u);
      }
    }
  }
  __syncthreads();

  // Flush: packed u32 -> unpacked global u32 atomics, skip zeros.
  const int b = blockIdx.x >> 7;               // / BLKS_PER_B
  unsigned* g0 = gh0 + (size_t)b * HSLOT;
  unsigned* g1 = gh1 + (size_t)b * HSLOT;
  for (int i = tid; i < HSLOT; i += 512) {
    const unsigned v = hist[i] + hist[i + HSLOT + 1];
    if (v) {
      const unsigned lo = v & 0xFFFFu;
      const unsigned hi = v >> 16;
      if (lo) atomicAdd(&g0[i], lo);
      if (hi) atomicAdd(&g1[i], hi);
    }
  }
}

// ---------------------------------------------------------------------------
// Kernel 2: one block (256 thr) per (b, class) row. Read 256-bucket counts,
// descending scan, closed-form Lovasz contribution.
// Entering bucket with k fg / m bg already seen (higher-error buckets), K total:
//   fg: term += n1*e/(K+m);  k += n1;
//   bg: term += (K-k)*e*n0/((K+m)*(K+m+n0));  m += n0;
// Rows with ci==0 publish validCount[b].
// ---------------------------------------------------------------------------
__global__ __launch_bounds__(256) void lovasz_scan_kernel(
    const unsigned* __restrict__ gh0, const unsigned* __restrict__ gh1,
    float* __restrict__ terms, unsigned* __restrict__ validCount) {
  __shared__ unsigned ts1[256];
  __shared__ unsigned ts0[256];
  __shared__ float redf[256];
  __shared__ int redi[256];

  const int tid = threadIdx.x;                 // owns bucket h = tid
  const int row = blockIdx.x;                  // b*20 + ci
  const int b = row / NCLS;
  const int ci = row % NCLS;

  const unsigned lo = gh0[(size_t)b * HSLOT + ci * HB + tid];  // bg count
  const unsigned hi = gh1[(size_t)b * HSLOT + ci * HB + tid];  // fg count

  const int r = 255 - tid;                     // descending rank
  ts1[r] = hi; ts0[r] = lo;
  __syncthreads();

  // Inclusive Hillis-Steele scan over descending rank.
  for (int off = 1; off < 256; off <<= 1) {
    unsigned a1 = 0, a0 = 0;
    if (r >= off) { a1 = ts1[r - off]; a0 = ts0[r - off]; }
    __syncthreads();
    ts1[r] += a1; ts0[r] += a0;
    __syncthreads();
  }
  const unsigned K = ts1[255];
  const unsigned V = K + ts0[255];
  if (tid == 0 && ci == 0) validCount[b] = V;

  float term = 0.f;
  if (K > 0) {
    unsigned k = ts1[r] - hi;                  // fg seen before my bucket
    const unsigned m = ts0[r] - lo;            // bg seen before my bucket
    const float e = ((float)tid + 0.5f) * (1.0f / (float)HB);
    if (hi) term += (float)hi * e / (float)(K + m);
    k += hi;
    if (lo) term += (float)(K - k) * e *
                    ((float)lo / ((float)(K + m) * (float)(K + m + lo)));
    redf[tid] = term;
    __syncthreads();
  } else {
    // Degenerate: no fg -> grad = [1,0,...] -> term = max error midpoint.
    redi[tid] = (lo | hi) ? tid : -1;
    redf[tid] = 0.f;
    __syncthreads();
    for (int off = 128; off > 0; off >>= 1) {
      if (tid < off) redi[tid] = redi[tid] > redi[tid + off] ? redi[tid] : redi[tid + off];
      __syncthreads();
    }
    if (tid == 0 && redi[0] >= 0)
      redf[0] = ((float)redi[0] + 0.5f) * (1.0f / (float)HB);
    __syncthreads();
  }

  for (int off = 128; off > 0; off >>= 1) {
    if (tid < off) redf[tid] += redf[tid + off];
    __syncthreads();
  }
  if (tid == 0) terms[row] = redf[0];
}

// ---------------------------------------------------------------------------
// Kernel 3: include-mask + final fixed-order reduction -> scalar loss.
// ---------------------------------------------------------------------------
__global__ __launch_bounds__(256) void lovasz_final_kernel(
    const float* __restrict__ terms, const unsigned* __restrict__ validCount,
    float* __restrict__ out) {
  __shared__ float red[256];
  const int t = threadIdx.x;
  float v = 0.f;
  if (t < B_DIM * NCLS) {
    const int b = t / NCLS;
    if (validCount[b] >= 2) v = terms[t];
  }
  red[t] = v;
  __syncthreads();
  for (int off = 128; off > 0; off >>= 1) {
    if (t < off) red[t] += red[t + off];
    __syncthreads();
  }
  if (t == 0) {
    int cnt = 0;
    #pragma unroll
    for (int b = 0; b < B_DIM; ++b) cnt += (validCount[b] >= 2) ? 1 : 0;
    const int count = cnt * NCLS;
    out[0] = red[0] / (float)(count > 0 ? count : 1);
  }
}

extern "C" void kernel_launch(void* const* d_in, const int* in_sizes, int n_in,
                              void* d_out, int out_size, void* d_ws, size_t ws_size,
                              hipStream_t stream) {
  const float* logits = (const float*)d_in[0];
  const int* labels = (const int*)d_in[1];
  float* out = (float*)d_out;

  char* ws = (char*)d_ws;
  unsigned* validCount = (unsigned*)ws;              // 8 * u32   @ 0
  float* terms = (float*)(ws + 64);                  // 160 * f32 @ 64
  unsigned* gh0 = (unsigned*)(ws + 1024);            // 8*5120 u32 = 160 KB
  unsigned* gh1 = (unsigned*)(ws + 1024 + 4 * B_DIM * HSLOT);  // 160 KB

  // Zero validCount + gh0 + gh1 in one async fill (covers [0, 1024+320KB)).
  hipMemsetAsync(ws, 0, 1024 + 8 * B_DIM * HSLOT, stream);

  lovasz_hist1_kernel<<<NBLK1, 512, 0, stream>>>(logits, labels, gh0, gh1);
  lovasz_scan_kernel<<<B_DIM * NCLS, 256, 0, stream>>>(gh0, gh1, terms, validCount);
  lovasz_final_kernel<<<1, 256, 0, stream>>>(terms, validCount, out);
}

// Round 5
// 42.430 us; speedup vs baseline: 1.3024x; 1.3024x over previous
//
#include <hip/hip_runtime.h>
#include <hip/hip_bf16.h>

// Lovasz-Softmax loss, B=8, N=262144 (2^18), C=21, ignore_index=0.
// R5: revert R4's global-atomic flush (same-address L2 atomic chains + a
// pathologically slow 321KB fill dispatch cost ~15us). Back to deterministic
// non-atomic per-block partials (R3 structure), but 512 blocks x 4096 px
// instead of 1024 x 2048 -> partials halved to 10.5MB, K2 merges 64/row.

#define B_DIM 8
#define N_DIM 262144          // 2^18
#define NCLS 20               // classes 1..20
#define HB 256                // buckets
#define PX_PER_BLK 4096       // K1: 512 threads x 8 pixels
#define BLKS_PER_B 64         // 262144 / 4096
#define NBLK1 (B_DIM * BLKS_PER_B)   // 512
#define HSLOT (NCLS * HB)     // 5120 u32 per histogram (un-skewed)

// ---------------------------------------------------------------------------
// Kernel 1: softmax + error bucketing -> per-block packed histograms.
// partial[blk][c-1][h] u32: lo16 = bg count, hi16 = fg count (<=4096 each).
// 2 LDS replicas split by half-wave, +1-u32 skew between replicas.
// ---------------------------------------------------------------------------
__global__ __launch_bounds__(512) void lovasz_hist1_kernel(
    const float* __restrict__ logits, const int* __restrict__ labels,
    unsigned* __restrict__ partials) {
  __shared__ unsigned hist[2 * HSLOT + 1];
  const int tid = threadIdx.x;

  for (int i = tid; i < 2 * HSLOT + 1; i += 512) hist[i] = 0;
  __syncthreads();

  unsigned* myh = hist + ((tid >> 5) & 1) * (HSLOT + 1);
  const size_t base = (size_t)blockIdx.x * PX_PER_BLK;

  #pragma unroll
  for (int j = 0; j < 8; ++j) {
    const size_t p = base + tid + j * 512;
    const int lab = labels[p];
    const float* lp = logits + p * 21;
    float ex[21];
    float denom = 0.f;
    #pragma unroll
    for (int c = 0; c < 21; ++c) {
      ex[c] = __expf(lp[c]);
      denom += ex[c];
    }
    const float inv = 1.0f / denom;
    if (lab != 0) {
      #pragma unroll
      for (int c = 1; c <= NCLS; ++c) {
        const float pc = ex[c] * inv;
        const bool fg = (lab == c);
        const float e = fg ? (1.0f - pc) : pc;     // in (0,1)
        int h = (int)(e * (float)HB);
        h = h < (HB - 1) ? h : (HB - 1);
        atomicAdd(&myh[(c - 1) * HB + h], fg ? 0x10000u : 1u);
      }
    }
  }
  __syncthreads();

  unsigned* outp = partials + (size_t)blockIdx.x * HSLOT;
  for (int i = tid; i < HSLOT; i += 512)
    outp[i] = hist[i] + hist[i + HSLOT + 1];
}

// ---------------------------------------------------------------------------
// Kernel 2: one block (256 thr) per (b, class) row. Merge 64 block-partials,
// descending scan over 256 buckets, closed-form Lovasz contribution.
// Entering bucket with k fg / m bg already seen (higher-error buckets), K total:
//   fg: term += n1*e/(K+m);  k += n1;
//   bg: term += (K-k)*e*n0/((K+m)*(K+m+n0));  m += n0;
// Rows with ci==0 publish validCount[b].
// ---------------------------------------------------------------------------
__global__ __launch_bounds__(256) void lovasz_scan_kernel(
    const unsigned* __restrict__ partials, float* __restrict__ terms,
    unsigned* __restrict__ validCount) {
  __shared__ unsigned ts1[256];
  __shared__ unsigned ts0[256];
  __shared__ float redf[256];
  __shared__ int redi[256];

  const int tid = threadIdx.x;                 // owns bucket h = tid
  const int row = blockIdx.x;                  // b*20 + ci
  const int b = row / NCLS;
  const int ci = row % NCLS;

  // Sum this row's bucket across the batch's 64 block-partials (unpack before
  // summing: packed lo-fields would overflow u16).
  unsigned lo = 0, hi = 0;
  const unsigned* pp = partials + (size_t)(b * BLKS_PER_B) * HSLOT + ci * HB + tid;
  #pragma unroll 8
  for (int blk = 0; blk < BLKS_PER_B; ++blk) {
    const unsigned v = pp[(size_t)blk * HSLOT];
    lo += v & 0xFFFFu;
    hi += v >> 16;
  }
  // n0 = lo (bg), n1 = hi (fg) for bucket tid.

  const int r = 255 - tid;                     // descending rank
  ts1[r] = hi; ts0[r] = lo;
  __syncthreads();

  // Inclusive Hillis-Steele scan over descending rank.
  for (int off = 1; off < 256; off <<= 1) {
    unsigned a1 = 0, a0 = 0;
    if (r >= off) { a1 = ts1[r - off]; a0 = ts0[r - off]; }
    __syncthreads();
    ts1[r] += a1; ts0[r] += a0;
    __syncthreads();
  }
  const unsigned K = ts1[255];
  const unsigned V = K + ts0[255];
  if (tid == 0 && ci == 0) validCount[b] = V;

  float term = 0.f;
  if (K > 0) {
    unsigned k = ts1[r] - hi;                  // fg seen before my bucket
    const unsigned m = ts0[r] - lo;            // bg seen before my bucket
    const float e = ((float)tid + 0.5f) * (1.0f / (float)HB);
    if (hi) term += (float)hi * e / (float)(K + m);
    k += hi;
    if (lo) term += (float)(K - k) * e *
                    ((float)lo / ((float)(K + m) * (float)(K + m + lo)));
    redf[tid] = term;
    __syncthreads();
  } else {
    // Degenerate: no fg -> grad = [1,0,...] -> term = max error midpoint.
    redi[tid] = (lo | hi) ? tid : -1;
    redf[tid] = 0.f;
    __syncthreads();
    for (int off = 128; off > 0; off >>= 1) {
      if (tid < off) redi[tid] = redi[tid] > redi[tid + off] ? redi[tid] : redi[tid + off];
      __syncthreads();
    }
    if (tid == 0 && redi[0] >= 0)
      redf[0] = ((float)redi[0] + 0.5f) * (1.0f / (float)HB);
    __syncthreads();
  }

  for (int off = 128; off > 0; off >>= 1) {
    if (tid < off) redf[tid] += redf[tid + off];
    __syncthreads();
  }
  if (tid == 0) terms[row] = redf[0];
}

// ---------------------------------------------------------------------------
// Kernel 3: include-mask + final fixed-order reduction -> scalar loss.
// ---------------------------------------------------------------------------
__global__ __launch_bounds__(256) void lovasz_final_kernel(
    const float* __restrict__ terms, const unsigned* __restrict__ validCount,
    float* __restrict__ out) {
  __shared__ float red[256];
  const int t = threadIdx.x;
  float v = 0.f;
  if (t < B_DIM * NCLS) {
    const int b = t / NCLS;
    if (validCount[b] >= 2) v = terms[t];
  }
  red[t] = v;
  __syncthreads();
  for (int off = 128; off > 0; off >>= 1) {
    if (t < off) red[t] += red[t + off];
    __syncthreads();
  }
  if (t == 0) {
    int cnt = 0;
    #pragma unroll
    for (int b = 0; b < B_DIM; ++b) cnt += (validCount[b] >= 2) ? 1 : 0;
    const int count = cnt * NCLS;
    out[0] = red[0] / (float)(count > 0 ? count : 1);
  }
}

extern "C" void kernel_launch(void* const* d_in, const int* in_sizes, int n_in,
                              void* d_out, int out_size, void* d_ws, size_t ws_size,
                              hipStream_t stream) {
  const float* logits = (const float*)d_in[0];
  const int* labels = (const int*)d_in[1];
  float* out = (float*)d_out;

  char* ws = (char*)d_ws;
  unsigned* validCount = (unsigned*)ws;              // 8 * u32 (written by K2)
  float* terms = (float*)(ws + 64);                  // 160 * f32
  unsigned* partials = (unsigned*)(ws + 1024);       // 512 * 5120 u32 = 10.5 MB

  lovasz_hist1_kernel<<<NBLK1, 512, 0, stream>>>(logits, labels, partials);
  lovasz_scan_kernel<<<B_DIM * NCLS, 256, 0, stream>>>(partials, terms, validCount);
  lovasz_final_kernel<<<1, 256, 0, stream>>>(terms, validCount, out);
}